// Round 15
// baseline (299.750 us; speedup 1.0000x reference)
//
#include <hip/hip_runtime.h>

// GCNLinkPredictor: 2-layer GCN, N=100000, E=3.2M, F=128, U=1000.
// R22: ATOMIC-FREE CSR fill.
//   R10's standalone fill: 1.07M device atomicAdds / 56us / 2.4GHz =
//   7.96/cycle == 8 == one per XCD. Fill is pinned at the chip's
//   device-atomic serialization rate — explains every null MLP
//   restructuring (R8-R10) and sum-not-max fusion (R11-R14).
//   Fix: positions are derivable from the histogram we already have.
//   pos = baseF[f][p] + rank, baseF[f][p] = rp[d] + sum_{q<p} cnt_q[d]
//   (prep_scan second pass over partials, 512B/frontier node), rank =
//   LDS packed-u8 returns-old counter within slice (cnt<=~8, exact).
//   fill = 128 blocks x 1024 thr mirroring hist slices; ZERO global
//   atomics. rp stays the exclusive prefix -> gathers use rp[node],
//   rp[node+1] with rp[n] sentinel. gemm1 un-fused back to its proven
//   standalone 256-thr body (fusion only ever gave sum-of-parts).
// Carried: fp8 xw1 (R21), nt streaming hints (R20), 1-pass u8 hist
// (R17), decoupled-lookback prep_scan (R16), Wt-in-LDS swizzled gemm +
// X->regs (R13), LDS bitmask flags (R10), passthrough fusion (R8),
// 8-way MLP gathers + fp16 h1c (R15).

#define F_DIM 128
#define U_USERS 1000
#define NFCAP 48000     // frontier cap (expected ~33K)
#define HW 25008        // u32 words of packed-u8 counters (covers 100032 nodes)
#define PSLICE 128      // edge slices == hist blocks == fill blocks
#define BMW 3136        // frontier bitmask words (= NBPS*64)
#define SMEM_BYTES 32768   // gemm Wt [128][128] fp16
#define NBPS 49         // prep_scan blocks (49*2048 >= 100000)

using f16x8 = __attribute__((ext_vector_type(8))) _Float16;
using f16x2 = __attribute__((ext_vector_type(2))) _Float16;
using f32x4 = __attribute__((ext_vector_type(4))) float;
using i32x4 = __attribute__((ext_vector_type(4))) int;

// ---- zero fr + lookback descriptors ----
__global__ __launch_bounds__(256) void zero_kernel(int* __restrict__ fr,
                                                   unsigned long long* __restrict__ desc,
                                                   int n) {
    int t = blockIdx.x * 256 + threadIdx.x;
    int n4 = n >> 2;
    if (t < n4) ((int4*)fr)[t] = make_int4(0, 0, 0, 0);
    if (t < (n & 3)) fr[(n & ~3) + t] = 0;
    if (t < NBPS) desc[t] = 0ull;
}

// ---- histogram: single pass, u8 LDS counters (4 nodes per word) ----
__global__ __launch_bounds__(1024) void hist_kernel(const int* __restrict__ src,
                                                    const int* __restrict__ dst,
                                                    unsigned int* __restrict__ partial,
                                                    int* __restrict__ fr, int E, int n) {
    __shared__ unsigned int h[HW];   // 100 KB
    int tid = threadIdx.x;
    int p = blockIdx.x;
    for (int i = tid; i < HW; i += 1024) h[i] = 0u;
    __syncthreads();

    int len = (E + PSLICE - 1) / PSLICE;   // 25000
    int base = p * len;
    int end = min(E, base + len);
    int e = base + tid * 4;
    for (; e + 3 < end; e += 4096) {
        i32x4 dv = __builtin_nontemporal_load((const i32x4*)(dst + e));
#pragma unroll
        for (int i = 0; i < 4; ++i) {
            int d = dv[i];
            if ((unsigned)d < (unsigned)n) {
                atomicAdd(&h[d >> 2], 1u << ((d & 3) << 3));
                if (d < U_USERS) {
                    int s = src[e + i];
                    if ((unsigned)s < (unsigned)n) fr[s] = 1;
                }
            }
        }
    }
    for (; e < end; ++e) {   // tail (generic safety)
        int d = dst[e];
        if ((unsigned)d < (unsigned)n) {
            atomicAdd(&h[d >> 2], 1u << ((d & 3) << 3));
            if (d < U_USERS) {
                int s = src[e];
                if ((unsigned)s < (unsigned)n) fr[s] = 1;
            }
        }
    }
    __syncthreads();
    unsigned int* outp = partial + (size_t)p * HW;
    for (int i = tid; i < HW; i += 1024) outp[i] = h[i];
}

// ---- merged prep + dual scan + baseF (decoupled lookback) ----
__global__ __launch_bounds__(1024) void prep_scan_kernel(
    const unsigned int* __restrict__ partial, const int* __restrict__ fr,
    float* __restrict__ inv, int* __restrict__ rp, int* __restrict__ remap,
    int* __restrict__ flist, int* __restrict__ nf_dev,
    unsigned int* __restrict__ bitsG, unsigned int* __restrict__ baseF,
    unsigned long long* __restrict__ desc, int n) {
    __shared__ unsigned long long ss[1024];
    __shared__ unsigned int bmw[64];
    __shared__ unsigned long long spre;
    int b = blockIdx.x, t = threadIdx.x;
    int i0 = b * 2048 + t * 2;
    bool in0 = i0 < n, in1 = i0 + 1 < n;

    unsigned a0 = 0, a1 = 0;
    if (in0) {
        int w = i0 >> 2;
        int sh = (i0 & 2) * 8;
        const unsigned int* bp = partial + w;
#pragma unroll 8
        for (int p = 0; p < PSLICE; ++p) {
            unsigned v = bp[(size_t)p * HW];
            a0 += (v >> sh) & 0xFFu;
            a1 += (v >> (sh + 8)) & 0xFFu;
        }
    }
    int fv0 = 0, fv1 = 0;
    if (in1) { int2 f2 = *(const int2*)(fr + i0); fv0 = f2.x; fv1 = f2.y; }
    else if (in0) fv0 = fr[i0];
    int isf0 = (in0 && ((i0 < U_USERS) || fv0)) ? 1 : 0;
    int isf1 = (in1 && ((i0 + 1 < U_USERS) || fv1)) ? 1 : 0;
    unsigned d0 = isf0 ? a0 : 0u, d1 = isf1 ? a1 : 0u;

    float r0v = rsqrtf((float)a0 + 1.f);
    float r1v = rsqrtf((float)a1 + 1.f);
    if (in1) *(float2*)(inv + i0) = make_float2(r0v, r1v);
    else if (in0) inv[i0] = r0v;

    if (t < 64) bmw[t] = 0u;
    __syncthreads();
    unsigned pbits = (unsigned)isf0 | ((unsigned)isf1 << 1);
    if (pbits) atomicOr(&bmw[(t * 2) >> 5], pbits << ((t * 2) & 31));
    __syncthreads();
    if (t < 64) bitsG[b * 64 + t] = bmw[t];

    unsigned long long myv = ((unsigned long long)(d0 + d1) << 20) |
                             (unsigned)(isf0 + isf1);
    ss[t] = myv;
    __syncthreads();
    for (int ofs = 1; ofs < 1024; ofs <<= 1) {
        unsigned long long v = (t >= ofs) ? ss[t - ofs] : 0ull;
        __syncthreads(); ss[t] += v; __syncthreads();
    }
    unsigned long long total = ss[1023];

    if (t == 0) atomicExch(&desc[b], (total << 1) | 1ull);
    if (t < 64) {
        int pblk = b - 1 - t;
        unsigned long long v = 0ull;
        if (pblk >= 0) {
            unsigned long long d;
            do { d = atomicAdd(&desc[pblk], 0ull); } while (!(d & 1ull));
            v = d >> 1;
        }
#pragma unroll
        for (int o = 32; o > 0; o >>= 1) v += __shfl_down(v, o);
        if (t == 0) spre = v;
    }
    __syncthreads();

    unsigned long long ex = spre + ss[t] - myv;
    int rp0 = (int)(ex >> 20), rm0 = (int)(ex & 0xFFFFFu);
    unsigned long long ex1 = ex + ((((unsigned long long)d0) << 20) | (unsigned)isf0);
    int rp1 = (int)(ex1 >> 20), rm1 = (int)(ex1 & 0xFFFFFu);
    if (in1) {
        *(int2*)(rp + i0) = make_int2(rp0, rp1);
        *(int2*)(remap + i0) = make_int2(rm0, rm1);
    } else if (in0) { rp[i0] = rp0; remap[i0] = rm0; }
    if (isf0 && rm0 < NFCAP) flist[rm0] = i0;
    if (isf1 && rm1 < NFCAP) flist[rm1] = i0 + 1;
    if (in0 && i0 == n - 1) *nf_dev = min(rm0 + isf0, NFCAP);
    if (in1 && i0 + 1 == n - 1) *nf_dev = min(rm1 + isf1, NFCAP);
    if (b == NBPS - 1 && t == 1023) rp[n] = (int)((spre + total) >> 20);  // sentinel

    // baseF pass: per frontier node, running prefix across slices
    if (isf0 && rm0 < NFCAP) {
        unsigned run = (unsigned)rp0;
        const unsigned int* bp = partial + (i0 >> 2);
        int sh0 = (i0 & 3) << 3;
        unsigned int* bf = baseF + (size_t)rm0 * PSLICE;
#pragma unroll 8
        for (int p = 0; p < PSLICE; ++p) {
            bf[p] = run;
            run += (bp[(size_t)p * HW] >> sh0) & 0xFFu;
        }
    }
    if (isf1 && rm1 < NFCAP) {
        unsigned run = (unsigned)rp1;
        const unsigned int* bp = partial + ((i0 + 1) >> 2);
        int sh1 = ((i0 + 1) & 3) << 3;
        unsigned int* bf = baseF + (size_t)rm1 * PSLICE;
#pragma unroll 8
        for (int p = 0; p < PSLICE; ++p) {
            bf[p] = run;
            run += (bp[(size_t)p * HW] >> sh1) & 0xFFu;
        }
    }
}

// ---- CSR fill, ATOMIC-FREE: block == hist slice, rank from LDS u8 ----
__global__ __launch_bounds__(1024) void fill_csr_kernel(const int* __restrict__ src,
                                                        const int* __restrict__ dst,
                                                        const unsigned int* __restrict__ bitsG,
                                                        const int* __restrict__ remap,
                                                        const unsigned int* __restrict__ baseF,
                                                        int* __restrict__ col, int E, int n) {
    __shared__ unsigned int bm[BMW];       // 12.5 KB frontier bitmask
    __shared__ unsigned int cnt[12288];    // 48 KB packed-u8 rank counters by f
    int tid = threadIdx.x;
    int p = blockIdx.x;
    for (int i = tid; i < BMW; i += 1024) bm[i] = bitsG[i];
    for (int i = tid; i < 12288; i += 1024) cnt[i] = 0u;
    __syncthreads();

    int len = (E + PSLICE - 1) / PSLICE;   // 25000
    int base = p * len;
    int end = min(E, base + len);
    int e = base + tid * 4;
    for (; e + 3 < end; e += 4096) {
        i32x4 dv = __builtin_nontemporal_load((const i32x4*)(dst + e));
        i32x4 sv = __builtin_nontemporal_load((const i32x4*)(src + e));
#pragma unroll
        for (int i = 0; i < 4; ++i) {
            int d = dv[i];
            if (((unsigned)d < (unsigned)n) && ((bm[d >> 5] >> (d & 31)) & 1u)) {
                int f = remap[d];
                if ((unsigned)f < (unsigned)NFCAP) {
                    unsigned bs = baseF[(size_t)f * PSLICE + p];
                    int sh = (f & 3) << 3;
                    unsigned old = atomicAdd(&cnt[f >> 2], 1u << sh);   // LDS only
                    unsigned rank = (old >> sh) & 0xFFu;
                    unsigned pos = bs + rank;
                    int s = sv[i];
                    if (pos < (unsigned)E) col[pos] = ((unsigned)s < (unsigned)n) ? s : 0;
                }
            }
        }
    }
    for (; e < end; ++e) {   // tail (generic safety)
        int d = dst[e];
        if (((unsigned)d < (unsigned)n) && ((bm[d >> 5] >> (d & 31)) & 1u)) {
            int f = remap[d];
            if ((unsigned)f < (unsigned)NFCAP) {
                unsigned bs = baseF[(size_t)f * PSLICE + p];
                int sh = (f & 3) << 3;
                unsigned old = atomicAdd(&cnt[f >> 2], 1u << sh);
                unsigned rank = (old >> sh) & 0xFFu;
                unsigned pos = bs + rank;
                int s = src[e];
                if (pos < (unsigned)E) col[pos] = ((unsigned)s < (unsigned)n) ? s : 0;
            }
        }
    }
}

// ---- Wt staging helper: [128][128] fp16, group g of row n at g^(n&15) ----
__device__ __forceinline__ void stage_wt(const float* __restrict__ W, _Float16* Wt, int tid) {
#pragma unroll
    for (int i = 0; i < 8; ++i) {
        int j = tid + 256 * i;        // 0..2047
        int nr = j & 127;
        int k8 = j >> 7;              // 0..15
        f16x8 v;
#pragma unroll
        for (int kk = 0; kk < 8; ++kk)
            v[kk] = (_Float16)W[(k8 * 8 + kk) * F_DIM + nr];
        *(f16x8*)&Wt[nr * F_DIM + ((k8 ^ (nr & 15)) * 8)] = v;
    }
}

// ---- MFMA fp16 GEMM (fp32 input): xw8 = fp8(X @ W), standalone ----
__global__ __launch_bounds__(256) void gemm_f16_kernel(const float* __restrict__ X,
                                                       const float* __restrict__ W,
                                                       unsigned char* __restrict__ out8,
                                                       float* __restrict__ pout, int nrows) {
    __shared__ __align__(16) unsigned char smem[SMEM_BYTES];
    _Float16* Wt = (_Float16*)smem;
    int tid = threadIdx.x;
    int rowBase = blockIdx.x * 64;
    stage_wt(W, Wt, tid);
    __syncthreads();

    int w = tid >> 6;
    int lane = tid & 63;
    int m = lane & 15;
    int quad = lane >> 4;
    int row = rowBase + w * 16 + m;
    bool rv = row < nrows;

    f16x8 a0, a1, a2, a3;
    {
        const float* xr = X + (size_t)row * F_DIM;
        float* pr = (rv && row >= U_USERS) ? pout + (size_t)row * F_DIM : nullptr;
#pragma unroll
        for (int kc = 0; kc < 4; ++kc) {
            f32x4 lo = (f32x4){0.f, 0.f, 0.f, 0.f};
            f32x4 hi = lo;
            if (rv) {
                lo = __builtin_nontemporal_load((const f32x4*)(xr + kc * 32 + quad * 8));
                hi = __builtin_nontemporal_load((const f32x4*)(xr + kc * 32 + quad * 8) + 1);
            }
            if (pr) {
                __builtin_nontemporal_store(lo, (f32x4*)(pr + kc * 32 + quad * 8));
                __builtin_nontemporal_store(hi, (f32x4*)(pr + kc * 32 + quad * 8) + 1);
            }
            f16x8 av;
            av[0] = (_Float16)lo[0]; av[1] = (_Float16)lo[1];
            av[2] = (_Float16)lo[2]; av[3] = (_Float16)lo[3];
            av[4] = (_Float16)hi[0]; av[5] = (_Float16)hi[1];
            av[6] = (_Float16)hi[2]; av[7] = (_Float16)hi[3];
            if (kc == 0) a0 = av; else if (kc == 1) a1 = av;
            else if (kc == 2) a2 = av; else a3 = av;
        }
    }

    f32x4 acc[8];
#pragma unroll
    for (int i = 0; i < 8; ++i) acc[i] = (f32x4){0.f, 0.f, 0.f, 0.f};

#pragma unroll
    for (int kc = 0; kc < 4; ++kc) {
        f16x8 a = (kc == 0) ? a0 : (kc == 1) ? a1 : (kc == 2) ? a2 : a3;
#pragma unroll
        for (int ct = 0; ct < 8; ++ct) {
            f16x8 b = *(const f16x8*)&Wt[(ct * 16 + m) * F_DIM +
                                         (((kc * 4 + quad) ^ m) * 8)];
            acc[ct] = __builtin_amdgcn_mfma_f32_16x16x32_f16(a, b, acc[ct], 0, 0, 0);
        }
    }

#pragma unroll
    for (int ct = 0; ct < 8; ++ct) {
#pragma unroll
        for (int reg = 0; reg < 4; ++reg) {
            int r = rowBase + w * 16 + quad * 4 + reg;
            if (r < nrows) {
                float v = acc[ct][reg];
                int p8 = __builtin_amdgcn_cvt_pk_fp8_f32(v, v, 0, false);
                out8[(size_t)r * F_DIM + ct * 16 + m] = (unsigned char)(p8 & 0xFF);
            }
        }
    }
}

// ---- MFMA fp16 GEMM (fp16 input rows, layer 2) ----
__global__ __launch_bounds__(256) void gemm_f16_dyn_kernel(const _Float16* __restrict__ Xh,
                                                           const float* __restrict__ W,
                                                           _Float16* __restrict__ outh,
                                                           const int* __restrict__ nrows_p) {
    __shared__ __align__(16) unsigned char smem[SMEM_BYTES];
    _Float16* Wt = (_Float16*)smem;
    int nrows = *nrows_p;
    int rowBase = blockIdx.x * 64;
    if (rowBase >= nrows) return;
    int tid = threadIdx.x;
    stage_wt(W, Wt, tid);
    __syncthreads();

    int w = tid >> 6;
    int lane = tid & 63;
    int m = lane & 15;
    int quad = lane >> 4;
    int row = rowBase + w * 16 + m;
    const _Float16* xr = Xh + (size_t)row * F_DIM;

    f32x4 acc[8];
#pragma unroll
    for (int i = 0; i < 8; ++i) acc[i] = (f32x4){0.f, 0.f, 0.f, 0.f};

#pragma unroll
    for (int kc = 0; kc < 4; ++kc) {
        f16x8 a = *(const f16x8*)(xr + kc * 32 + quad * 8);
#pragma unroll
        for (int ct = 0; ct < 8; ++ct) {
            f16x8 b = *(const f16x8*)&Wt[(ct * 16 + m) * F_DIM +
                                         (((kc * 4 + quad) ^ m) * 8)];
            acc[ct] = __builtin_amdgcn_mfma_f32_16x16x32_f16(a, b, acc[ct], 0, 0, 0);
        }
    }

#pragma unroll
    for (int ct = 0; ct < 8; ++ct) {
#pragma unroll
        for (int reg = 0; reg < 4; ++reg) {
            int r = rowBase + w * 16 + quad * 4 + reg;
            if (r < nrows)
                outh[(size_t)r * F_DIM + ct * 16 + m] = (_Float16)acc[ct][reg];
        }
    }
}

// ---- layer-1 gather (fp8 rows, fp32 accum), 8-way MLP ----
__global__ __launch_bounds__(256) void gather_l1_kernel(const unsigned char* __restrict__ xw8,
                                                        const float* __restrict__ inv,
                                                        const int* __restrict__ rp,
                                                        const int* __restrict__ col,
                                                        const int* __restrict__ flist,
                                                        const int* __restrict__ nf_p,
                                                        const float* __restrict__ b,
                                                        _Float16* __restrict__ h1c) {
    int ci = blockIdx.x * 4 + (threadIdx.x >> 6);
    if (ci >= *nf_p) return;
    int lane = threadIdx.x & 63;
    int node = flist[ci];
    int start = rp[node];
    int end = rp[node + 1];

    float accx = 0.f, accy = 0.f;
    for (int base = start; base < end; base += 64) {
        int j = base + lane;
        int s_l = 0; float c_l = 0.f;
        if (j < end) { s_l = __builtin_nontemporal_load(col + j); c_l = inv[s_l]; }
        int cnt = min(64, end - base);
        int i = 0;
        for (; i + 8 <= cnt; i += 8) {
            int ss[8]; float ff[8]; unsigned short vv[8];
#pragma unroll
            for (int u = 0; u < 8; ++u) { ss[u] = __shfl(s_l, i + u); ff[u] = __shfl(c_l, i + u); }
#pragma unroll
            for (int u = 0; u < 8; ++u)
                vv[u] = ((const unsigned short*)(xw8 + (size_t)ss[u] * F_DIM))[lane];
#pragma unroll
            for (int u = 0; u < 8; ++u) {
                accx += __builtin_amdgcn_cvt_f32_fp8((int)vv[u], 0) * ff[u];
                accy += __builtin_amdgcn_cvt_f32_fp8((int)vv[u], 1) * ff[u];
            }
        }
        for (; i + 4 <= cnt; i += 4) {
            int ss[4]; float ff[4]; unsigned short vv[4];
#pragma unroll
            for (int u = 0; u < 4; ++u) { ss[u] = __shfl(s_l, i + u); ff[u] = __shfl(c_l, i + u); }
#pragma unroll
            for (int u = 0; u < 4; ++u)
                vv[u] = ((const unsigned short*)(xw8 + (size_t)ss[u] * F_DIM))[lane];
#pragma unroll
            for (int u = 0; u < 4; ++u) {
                accx += __builtin_amdgcn_cvt_f32_fp8((int)vv[u], 0) * ff[u];
                accy += __builtin_amdgcn_cvt_f32_fp8((int)vv[u], 1) * ff[u];
            }
        }
        for (; i < cnt; ++i) {
            int s0 = __shfl(s_l, i); float f0 = __shfl(c_l, i);
            unsigned short v0 = ((const unsigned short*)(xw8 + (size_t)s0 * F_DIM))[lane];
            accx += __builtin_amdgcn_cvt_f32_fp8((int)v0, 0) * f0;
            accy += __builtin_amdgcn_cvt_f32_fp8((int)v0, 1) * f0;
        }
    }

    float ivd = inv[node];
    unsigned short selfraw = ((const unsigned short*)(xw8 + (size_t)node * F_DIM))[lane];
    float s0 = __builtin_amdgcn_cvt_f32_fp8((int)selfraw, 0);
    float s1 = __builtin_amdgcn_cvt_f32_fp8((int)selfraw, 1);
    float vx = accx * ivd + s0 * ivd * ivd + b[lane * 2];
    float vy = accy * ivd + s1 * ivd * ivd + b[lane * 2 + 1];
    vx = vx > 0.f ? vx : expf(vx) - 1.f;
    vy = vy > 0.f ? vy : expf(vy) - 1.f;
    f16x2 o; o[0] = (_Float16)vx; o[1] = (_Float16)vy;
    ((f16x2*)(h1c + (size_t)ci * F_DIM))[lane] = o;
}

// ---- layer-2 gather over rows [0,U) (fp16 compact rows), 8-way MLP ----
__global__ __launch_bounds__(256) void gather_l2_kernel(const _Float16* __restrict__ xwc,
                                                        const float* __restrict__ inv,
                                                        const int* __restrict__ rp,
                                                        const int* __restrict__ col,
                                                        const int* __restrict__ remap,
                                                        const float* __restrict__ b,
                                                        float* __restrict__ out) {
    int node = blockIdx.x * 4 + (threadIdx.x >> 6);
    if (node >= U_USERS) return;
    int lane = threadIdx.x & 63;
    int start = rp[node];
    int end = rp[node + 1];

    float accx = 0.f, accy = 0.f;
    for (int base = start; base < end; base += 64) {
        int j = base + lane;
        int r_l = 0; float c_l = 0.f;
        if (j < end) { int s = __builtin_nontemporal_load(col + j); c_l = inv[s]; r_l = remap[s]; }
        int cnt = min(64, end - base);
        int i = 0;
        for (; i + 8 <= cnt; i += 8) {
            int rr[8]; float ff[8]; f16x2 vv[8];
#pragma unroll
            for (int u = 0; u < 8; ++u) { rr[u] = __shfl(r_l, i + u); ff[u] = __shfl(c_l, i + u); }
#pragma unroll
            for (int u = 0; u < 8; ++u) vv[u] = ((const f16x2*)(xwc + (size_t)rr[u] * F_DIM))[lane];
#pragma unroll
            for (int u = 0; u < 8; ++u) { accx += (float)vv[u][0] * ff[u]; accy += (float)vv[u][1] * ff[u]; }
        }
        for (; i + 4 <= cnt; i += 4) {
            int rr[4]; float ff[4]; f16x2 vv[4];
#pragma unroll
            for (int u = 0; u < 4; ++u) { rr[u] = __shfl(r_l, i + u); ff[u] = __shfl(c_l, i + u); }
#pragma unroll
            for (int u = 0; u < 4; ++u) vv[u] = ((const f16x2*)(xwc + (size_t)rr[u] * F_DIM))[lane];
#pragma unroll
            for (int u = 0; u < 4; ++u) { accx += (float)vv[u][0] * ff[u]; accy += (float)vv[u][1] * ff[u]; }
        }
        for (; i < cnt; ++i) {
            int r0 = __shfl(r_l, i); float f0 = __shfl(c_l, i);
            f16x2 v0 = ((const f16x2*)(xwc + (size_t)r0 * F_DIM))[lane];
            accx += (float)v0[0] * f0;
            accy += (float)v0[1] * f0;
        }
    }

    float ivd = inv[node];
    f16x2 self = ((const f16x2*)(xwc + (size_t)node * F_DIM))[lane];  // remap[node]==node for node<U
    float vx = accx * ivd + (float)self[0] * ivd * ivd + b[lane * 2];
    float vy = accy * ivd + (float)self[1] * ivd * ivd + b[lane * 2 + 1];
    vx = vx > 0.f ? vx : expf(vx) - 1.f;
    vy = vy > 0.f ? vy : expf(vy) - 1.f;
    ((float2*)(out + (size_t)node * F_DIM))[lane] = make_float2(vx, vy);
}

extern "C" void kernel_launch(void* const* d_in, const int* in_sizes, int n_in,
                              void* d_out, int out_size, void* d_ws, size_t ws_size,
                              hipStream_t stream) {
    const float* x  = (const float*)d_in[0];
    const int*   ei = (const int*)d_in[1];   // [2, E] int32
    const float* W1 = (const float*)d_in[2];
    const float* b1 = (const float*)d_in[3];
    const float* W2 = (const float*)d_in[4];
    const float* b2 = (const float*)d_in[5];
    float* out = (float*)d_out;

    int n = in_sizes[0] / F_DIM;   // 100000
    int E = in_sizes[1] / 2;       // 3200000
    const int* srcI = ei;
    const int* dstI = ei + E;

    // workspace layout (~90 MB)
    unsigned char* xw8 = (unsigned char*)d_ws;       // n*128 fp8 (12.8MB)
    _Float16* xwc = (_Float16*)(xw8 + (size_t)n * F_DIM);   // NFCAP*128 f16
    _Float16* h1c = xwc + (size_t)NFCAP * F_DIM;     // NFCAP*128 f16
    float* inv   = (float*)(h1c + (size_t)NFCAP * F_DIM);  // n f
    int* fr      = (int*)(inv + n);                  // n
    int* remap   = fr + n;                           // n
    int* rp      = remap + n;                        // n+16 (sentinel at [n])
    int* flist   = rp + n + 16;                      // NFCAP
    int* nf_dev  = flist + NFCAP;                    // 16 ints
    int* col     = nf_dev + 16;                      // E
    unsigned int* partialH = (unsigned int*)(col + E);  // PSLICE*HW (12.8MB)
    unsigned int* bitsG = partialH + (size_t)PSLICE * HW;  // BMW words
    unsigned long long* desc = (unsigned long long*)(bitsG + BMW);  // NBPS u64
    unsigned int* baseF = (unsigned int*)(desc + NBPS + 7);  // NFCAP*PSLICE u32 (24.6MB)

    zero_kernel<<<(n / 4 + 255) / 256, 256, 0, stream>>>(fr, desc, n);

    hist_kernel<<<PSLICE, 1024, 0, stream>>>(srcI, dstI, partialH, fr, E, n);

    prep_scan_kernel<<<NBPS, 1024, 0, stream>>>(partialH, fr, inv, rp, remap,
                                                flist, nf_dev, bitsG, baseF, desc, n);

    fill_csr_kernel<<<PSLICE, 1024, 0, stream>>>(srcI, dstI, bitsG, remap, baseF, col, E, n);

    gemm_f16_kernel<<<(n + 63) / 64, 256, 0, stream>>>(x, W1, xw8, out, n);

    gather_l1_kernel<<<(NFCAP + 3) / 4, 256, 0, stream>>>(xw8, inv, rp, col, flist, nf_dev, b1, h1c);

    gemm_f16_dyn_kernel<<<(NFCAP + 63) / 64, 256, 0, stream>>>(h1c, W2, xwc, nf_dev);
    gather_l2_kernel<<<(U_USERS + 3) / 4, 256, 0, stream>>>(xwc, inv, rp, col, remap, b2, out);
}

// Round 16
// 246.634 us; speedup vs baseline: 1.2154x; 1.2154x over previous
//
#include <hip/hip_runtime.h>

// GCNLinkPredictor: 2-layer GCN, N=100000, E=3.2M, F=128, U=1000.
// R23: REVERT to R21 (best verified: 248.2us, absmax 0.0039).
//   R22 (atomic-free fill) regressed to 300us: prep_scan's baseF pass
//   ran at 4.4% occupancy (49 blocks) with serial 128-iter dependent
//   loops -> 59.5us; plus un-fusion gap and 1.07M random baseF reads in
//   fill. Structural verdict: fill is pinned by device-atomic rate
//   (~8/cycle) + line-granular scatter writeback; gemm+fill co-schedule
//   at sum-not-max; gathers are largely cache-resident. R21 is the
//   efficient frontier of what these constraints allow.
// Stack: fp8 xw1 (R21), nt streaming hints (R20), 1-pass u8 hist (R17),
// decoupled-lookback prep_scan (R16), role-interleaved gemm+fill fusion
// (R14), Wt-in-LDS swizzled gemm + X->regs (R13), LDS bitmask flags
// (R10), split-phase atomics (R9), passthrough fusion (R8), 8-way MLP
// gathers + fp16 h1c (R15).

#define F_DIM 128
#define U_USERS 1000
#define NFCAP 48000     // frontier cap (expected ~33K)
#define HW 25008        // u32 words of packed-u8 counters (covers 100032 nodes)
#define PSLICE 128      // edge slices -> 128 hist blocks
#define BMW 3136        // frontier bitmask words (= NBPS*64)
#define SMEM_BYTES 32768   // Wt [128][128] fp16 (>= bitmask 12544)
#define NBPS 49         // prep_scan blocks (49*2048 >= 100000)

using f16x8 = __attribute__((ext_vector_type(8))) _Float16;
using f16x2 = __attribute__((ext_vector_type(2))) _Float16;
using f32x4 = __attribute__((ext_vector_type(4))) float;
using i32x4 = __attribute__((ext_vector_type(4))) int;

// ---- zero fr + lookback descriptors ----
__global__ __launch_bounds__(256) void zero_kernel(int* __restrict__ fr,
                                                   unsigned long long* __restrict__ desc,
                                                   int n) {
    int t = blockIdx.x * 256 + threadIdx.x;
    int n4 = n >> 2;
    if (t < n4) ((int4*)fr)[t] = make_int4(0, 0, 0, 0);
    if (t < (n & 3)) fr[(n & ~3) + t] = 0;
    if (t < NBPS) desc[t] = 0ull;
}

// ---- histogram: single pass, u8 LDS counters (4 nodes per word) ----
__global__ __launch_bounds__(1024) void hist_kernel(const int* __restrict__ src,
                                                    const int* __restrict__ dst,
                                                    unsigned int* __restrict__ partial,
                                                    int* __restrict__ fr, int E, int n) {
    __shared__ unsigned int h[HW];   // 100 KB
    int tid = threadIdx.x;
    int p = blockIdx.x;
    for (int i = tid; i < HW; i += 1024) h[i] = 0u;
    __syncthreads();

    int len = (E + PSLICE - 1) / PSLICE;   // 25000
    int base = p * len;
    int end = min(E, base + len);
    int e = base + tid * 4;
    for (; e + 3 < end; e += 4096) {
        i32x4 dv = __builtin_nontemporal_load((const i32x4*)(dst + e));
#pragma unroll
        for (int i = 0; i < 4; ++i) {
            int d = dv[i];
            if ((unsigned)d < (unsigned)n) {
                atomicAdd(&h[d >> 2], 1u << ((d & 3) << 3));
                if (d < U_USERS) {
                    int s = src[e + i];
                    if ((unsigned)s < (unsigned)n) fr[s] = 1;
                }
            }
        }
    }
    for (; e < end; ++e) {   // tail (generic safety)
        int d = dst[e];
        if ((unsigned)d < (unsigned)n) {
            atomicAdd(&h[d >> 2], 1u << ((d & 3) << 3));
            if (d < U_USERS) {
                int s = src[e];
                if ((unsigned)s < (unsigned)n) fr[s] = 1;
            }
        }
    }
    __syncthreads();
    unsigned int* outp = partial + (size_t)p * HW;
    for (int i = tid; i < HW; i += 1024) outp[i] = h[i];
}

// ---- merged prep + dual scan (decoupled lookback, one dispatch) ----
__global__ __launch_bounds__(1024) void prep_scan_kernel(
    const unsigned int* __restrict__ partial, const int* __restrict__ fr,
    float* __restrict__ inv, int* __restrict__ rp, int* __restrict__ remap,
    int* __restrict__ flist, int* __restrict__ nf_dev,
    unsigned int* __restrict__ bitsG, unsigned long long* __restrict__ desc, int n) {
    __shared__ unsigned long long ss[1024];
    __shared__ unsigned int bmw[64];
    __shared__ unsigned long long spre;
    int b = blockIdx.x, t = threadIdx.x;
    int i0 = b * 2048 + t * 2;
    bool in0 = i0 < n, in1 = i0 + 1 < n;

    // deg for both nodes: sum u8 lanes over 128 slice partials
    unsigned a0 = 0, a1 = 0;
    if (in0) {
        int w = i0 >> 2;
        int sh = (i0 & 2) * 8;   // i0 even -> lanes (0,1) or (2,3)
        const unsigned int* bp = partial + w;
#pragma unroll 8
        for (int p = 0; p < PSLICE; ++p) {
            unsigned v = bp[(size_t)p * HW];
            a0 += (v >> sh) & 0xFFu;
            a1 += (v >> (sh + 8)) & 0xFFu;
        }
    }
    int fv0 = 0, fv1 = 0;
    if (in1) { int2 f2 = *(const int2*)(fr + i0); fv0 = f2.x; fv1 = f2.y; }
    else if (in0) fv0 = fr[i0];
    int isf0 = (in0 && ((i0 < U_USERS) || fv0)) ? 1 : 0;
    int isf1 = (in1 && ((i0 + 1 < U_USERS) || fv1)) ? 1 : 0;
    unsigned d0 = isf0 ? a0 : 0u, d1 = isf1 ? a1 : 0u;

    float r0v = rsqrtf((float)a0 + 1.f);
    float r1v = rsqrtf((float)a1 + 1.f);
    if (in1) *(float2*)(inv + i0) = make_float2(r0v, r1v);
    else if (in0) inv[i0] = r0v;

    // frontier bitmask: block owns 64 whole words (2048 nodes)
    if (t < 64) bmw[t] = 0u;
    __syncthreads();
    unsigned pbits = (unsigned)isf0 | ((unsigned)isf1 << 1);
    if (pbits) atomicOr(&bmw[(t * 2) >> 5], pbits << ((t * 2) & 31));
    __syncthreads();
    if (t < 64) bitsG[b * 64 + t] = bmw[t];

    // packed inclusive scan over 1024 per-thread pair-sums
    unsigned long long myv = ((unsigned long long)(d0 + d1) << 20) |
                             (unsigned)(isf0 + isf1);
    ss[t] = myv;
    __syncthreads();
    for (int ofs = 1; ofs < 1024; ofs <<= 1) {
        unsigned long long v = (t >= ofs) ? ss[t - ofs] : 0ull;
        __syncthreads(); ss[t] += v; __syncthreads();
    }
    unsigned long long total = ss[1023];

    // publish aggregate; windowed lookback (<= 48 predecessors < 64 lanes)
    if (t == 0) atomicExch(&desc[b], (total << 1) | 1ull);
    if (t < 64) {
        int pblk = b - 1 - t;
        unsigned long long v = 0ull;
        if (pblk >= 0) {
            unsigned long long d;
            do { d = atomicAdd(&desc[pblk], 0ull); } while (!(d & 1ull));
            v = d >> 1;
        }
#pragma unroll
        for (int o = 32; o > 0; o >>= 1) v += __shfl_down(v, o);
        if (t == 0) spre = v;
    }
    __syncthreads();

    unsigned long long ex = spre + ss[t] - myv;   // exclusive prefix at node i0
    int rp0 = (int)(ex >> 20), rm0 = (int)(ex & 0xFFFFFu);
    unsigned long long ex1 = ex + ((((unsigned long long)d0) << 20) | (unsigned)isf0);
    int rp1 = (int)(ex1 >> 20), rm1 = (int)(ex1 & 0xFFFFFu);
    if (in1) {
        *(int2*)(rp + i0) = make_int2(rp0, rp1);
        *(int2*)(remap + i0) = make_int2(rm0, rm1);
    } else if (in0) { rp[i0] = rp0; remap[i0] = rm0; }
    if (isf0 && rm0 < NFCAP) flist[rm0] = i0;
    if (isf1 && rm1 < NFCAP) flist[rm1] = i0 + 1;
    if (in0 && i0 == n - 1) *nf_dev = min(rm0 + isf0, NFCAP);
    if (in1 && i0 + 1 == n - 1) *nf_dev = min(rm1 + isf1, NFCAP);
}

// ---- fill_csr body: LDS bitmask flags + 4 edges/thread split-phase ----
__device__ __forceinline__ void fill_csr_body(const int* __restrict__ src,
                                              const int* __restrict__ dst,
                                              const unsigned int* __restrict__ bitsG,
                                              int* __restrict__ rp, int* __restrict__ col,
                                              int E, int n, int fblk,
                                              unsigned char* smem) {
    unsigned int* bm = (unsigned int*)smem;   // 12.5 KB of the union
    int tid = threadIdx.x;
    int nw = (n + 31) >> 5;
    for (int i = tid; i < nw; i += 256) bm[i] = bitsG[i];
    __syncthreads();

    int t = fblk * 256 + tid;
    int e0 = t * 4;
    if (e0 + 3 < E) {
        i32x4 dv = __builtin_nontemporal_load((const i32x4*)(dst + e0));
        i32x4 sv = __builtin_nontemporal_load((const i32x4*)(src + e0));
        bool f[4];
#pragma unroll
        for (int i = 0; i < 4; ++i) {
            int d = dv[i];
            f[i] = ((unsigned)d < (unsigned)n) && ((unsigned)sv[i] < (unsigned)n)
                   && ((bm[d >> 5] >> (d & 31)) & 1u);
        }
        int pos[4];
#pragma unroll
        for (int i = 0; i < 4; ++i) {
            pos[i] = -1;
            if (f[i]) pos[i] = atomicAdd(&rp[dv[i]], 1);
        }
#pragma unroll
        for (int i = 0; i < 4; ++i) {
            if (f[i] && (unsigned)pos[i] < (unsigned)E) col[pos[i]] = sv[i];
        }
    } else {
        for (int e = e0; e < E; ++e) {
            int d = dst[e], s = src[e];
            if ((unsigned)d < (unsigned)n && (unsigned)s < (unsigned)n &&
                ((bm[d >> 5] >> (d & 31)) & 1u)) {
                int pos = atomicAdd(&rp[d], 1);
                if ((unsigned)pos < (unsigned)E) col[pos] = s;
            }
        }
    }
}

// ---- Wt staging helper: [128][128] fp16, group g of row n at g^(n&15) ----
__device__ __forceinline__ void stage_wt(const float* __restrict__ W, _Float16* Wt, int tid) {
#pragma unroll
    for (int i = 0; i < 8; ++i) {
        int j = tid + 256 * i;        // 0..2047
        int nr = j & 127;
        int k8 = j >> 7;              // 0..15
        f16x8 v;
#pragma unroll
        for (int kk = 0; kk < 8; ++kk)
            v[kk] = (_Float16)W[(k8 * 8 + kk) * F_DIM + nr];
        *(f16x8*)&Wt[nr * F_DIM + ((k8 ^ (nr & 15)) * 8)] = v;
    }
}

// ---- MFMA fp16 GEMM body (fp32 input): xw8 = fp8(X @ W) ----
__device__ __forceinline__ void gemm_mfma_body(const float* __restrict__ X,
                                               const float* __restrict__ W,
                                               unsigned char* __restrict__ out8,
                                               float* __restrict__ pout,
                                               int nrows, int rowBase,
                                               unsigned char* smem) {
    _Float16* Wt = (_Float16*)smem;
    int tid = threadIdx.x;
    stage_wt(W, Wt, tid);
    __syncthreads();

    int w = tid >> 6;
    int lane = tid & 63;
    int m = lane & 15;
    int quad = lane >> 4;
    int row = rowBase + w * 16 + m;
    bool rv = row < nrows;

    f16x8 a0, a1, a2, a3;
    {
        const float* xr = X + (size_t)row * F_DIM;
        float* pr = (pout != nullptr && rv && row >= U_USERS)
                        ? pout + (size_t)row * F_DIM : nullptr;
#pragma unroll
        for (int kc = 0; kc < 4; ++kc) {
            f32x4 lo = (f32x4){0.f, 0.f, 0.f, 0.f};
            f32x4 hi = lo;
            if (rv) {
                lo = __builtin_nontemporal_load((const f32x4*)(xr + kc * 32 + quad * 8));
                hi = __builtin_nontemporal_load((const f32x4*)(xr + kc * 32 + quad * 8) + 1);
            }
            if (pr) {
                __builtin_nontemporal_store(lo, (f32x4*)(pr + kc * 32 + quad * 8));
                __builtin_nontemporal_store(hi, (f32x4*)(pr + kc * 32 + quad * 8) + 1);
            }
            f16x8 av;
            av[0] = (_Float16)lo[0]; av[1] = (_Float16)lo[1];
            av[2] = (_Float16)lo[2]; av[3] = (_Float16)lo[3];
            av[4] = (_Float16)hi[0]; av[5] = (_Float16)hi[1];
            av[6] = (_Float16)hi[2]; av[7] = (_Float16)hi[3];
            if (kc == 0) a0 = av; else if (kc == 1) a1 = av;
            else if (kc == 2) a2 = av; else a3 = av;
        }
    }

    f32x4 acc[8];
#pragma unroll
    for (int i = 0; i < 8; ++i) acc[i] = (f32x4){0.f, 0.f, 0.f, 0.f};

#pragma unroll
    for (int kc = 0; kc < 4; ++kc) {
        f16x8 a = (kc == 0) ? a0 : (kc == 1) ? a1 : (kc == 2) ? a2 : a3;
#pragma unroll
        for (int ct = 0; ct < 8; ++ct) {
            f16x8 b = *(const f16x8*)&Wt[(ct * 16 + m) * F_DIM +
                                         (((kc * 4 + quad) ^ m) * 8)];
            acc[ct] = __builtin_amdgcn_mfma_f32_16x16x32_f16(a, b, acc[ct], 0, 0, 0);
        }
    }

#pragma unroll
    for (int ct = 0; ct < 8; ++ct) {
#pragma unroll
        for (int reg = 0; reg < 4; ++reg) {
            int r = rowBase + w * 16 + quad * 4 + reg;
            if (r < nrows) {
                float v = acc[ct][reg];
                int p8 = __builtin_amdgcn_cvt_pk_fp8_f32(v, v, 0, false);
                out8[(size_t)r * F_DIM + ct * 16 + m] = (unsigned char)(p8 & 0xFF);
            }
        }
    }
}

// ---- MFMA fp16 GEMM body (fp16 input rows, layer 2, fp16 out) ----
__device__ __forceinline__ void gemm_mfma_body_h(const _Float16* __restrict__ Xh,
                                                 const float* __restrict__ W,
                                                 _Float16* __restrict__ outh,
                                                 int nrows, int rowBase,
                                                 unsigned char* smem) {
    _Float16* Wt = (_Float16*)smem;
    int tid = threadIdx.x;
    stage_wt(W, Wt, tid);
    __syncthreads();

    int w = tid >> 6;
    int lane = tid & 63;
    int m = lane & 15;
    int quad = lane >> 4;
    int row = rowBase + w * 16 + m;
    const _Float16* xr = Xh + (size_t)row * F_DIM;

    f32x4 acc[8];
#pragma unroll
    for (int i = 0; i < 8; ++i) acc[i] = (f32x4){0.f, 0.f, 0.f, 0.f};

#pragma unroll
    for (int kc = 0; kc < 4; ++kc) {
        f16x8 a = *(const f16x8*)(xr + kc * 32 + quad * 8);
#pragma unroll
        for (int ct = 0; ct < 8; ++ct) {
            f16x8 b = *(const f16x8*)&Wt[(ct * 16 + m) * F_DIM +
                                         (((kc * 4 + quad) ^ m) * 8)];
            acc[ct] = __builtin_amdgcn_mfma_f32_16x16x32_f16(a, b, acc[ct], 0, 0, 0);
        }
    }

#pragma unroll
    for (int ct = 0; ct < 8; ++ct) {
#pragma unroll
        for (int reg = 0; reg < 4; ++reg) {
            int r = rowBase + w * 16 + quad * 4 + reg;
            if (r < nrows)
                outh[(size_t)r * F_DIM + ct * 16 + m] = (_Float16)acc[ct][reg];
        }
    }
}

// ---- fused dispatch: Bresenham-interleaved roles ----
__global__ __launch_bounds__(256) void gemm_fill_kernel(const float* __restrict__ X,
                                                        const float* __restrict__ W,
                                                        unsigned char* __restrict__ out8,
                                                        float* __restrict__ pout, int nrows,
                                                        int gemmBlocks, int totalBlocks,
                                                        const int* __restrict__ src,
                                                        const int* __restrict__ dst,
                                                        const unsigned int* __restrict__ bitsG,
                                                        int* __restrict__ rp,
                                                        int* __restrict__ col, int E, int n) {
    __shared__ __align__(16) unsigned char smem[SMEM_BYTES];   // 32 KB union
    int b = blockIdx.x;
    long long g = gemmBlocks, T = totalBlocks;
    int before = (int)((long long)b * g / T);
    int after  = (int)(((long long)b + 1) * g / T);
    if (after > before) {
        gemm_mfma_body(X, W, out8, pout, nrows, before * 64, smem);
    } else {
        fill_csr_body(src, dst, bitsG, rp, col, E, n, b - before, smem);
    }
}

__global__ __launch_bounds__(256) void gemm_f16_dyn_kernel(const _Float16* __restrict__ Xh,
                                                           const float* __restrict__ W,
                                                           _Float16* __restrict__ outh,
                                                           const int* __restrict__ nrows_p) {
    __shared__ __align__(16) unsigned char smem[SMEM_BYTES];
    int nrows = *nrows_p;
    int rowBase = blockIdx.x * 64;
    if (rowBase >= nrows) return;
    gemm_mfma_body_h(Xh, W, outh, nrows, rowBase, smem);
}

// ---- layer-1 gather (fp8 rows, fp32 accum), 8-way MLP ----
__global__ __launch_bounds__(256) void gather_l1_kernel(const unsigned char* __restrict__ xw8,
                                                        const float* __restrict__ inv,
                                                        const int* __restrict__ rp,
                                                        const int* __restrict__ col,
                                                        const int* __restrict__ flist,
                                                        const int* __restrict__ nf_p,
                                                        const float* __restrict__ b,
                                                        _Float16* __restrict__ h1c) {
    int ci = blockIdx.x * 4 + (threadIdx.x >> 6);
    if (ci >= *nf_p) return;
    int lane = threadIdx.x & 63;
    int node = flist[ci];
    int start = (node == 0) ? 0 : rp[node - 1];
    int end = rp[node];

    float accx = 0.f, accy = 0.f;
    for (int base = start; base < end; base += 64) {
        int j = base + lane;
        int s_l = 0; float c_l = 0.f;
        if (j < end) { s_l = __builtin_nontemporal_load(col + j); c_l = inv[s_l]; }
        int cnt = min(64, end - base);
        int i = 0;
        for (; i + 8 <= cnt; i += 8) {
            int ss[8]; float ff[8]; unsigned short vv[8];
#pragma unroll
            for (int u = 0; u < 8; ++u) { ss[u] = __shfl(s_l, i + u); ff[u] = __shfl(c_l, i + u); }
#pragma unroll
            for (int u = 0; u < 8; ++u)
                vv[u] = ((const unsigned short*)(xw8 + (size_t)ss[u] * F_DIM))[lane];
#pragma unroll
            for (int u = 0; u < 8; ++u) {
                accx += __builtin_amdgcn_cvt_f32_fp8((int)vv[u], 0) * ff[u];
                accy += __builtin_amdgcn_cvt_f32_fp8((int)vv[u], 1) * ff[u];
            }
        }
        for (; i + 4 <= cnt; i += 4) {
            int ss[4]; float ff[4]; unsigned short vv[4];
#pragma unroll
            for (int u = 0; u < 4; ++u) { ss[u] = __shfl(s_l, i + u); ff[u] = __shfl(c_l, i + u); }
#pragma unroll
            for (int u = 0; u < 4; ++u)
                vv[u] = ((const unsigned short*)(xw8 + (size_t)ss[u] * F_DIM))[lane];
#pragma unroll
            for (int u = 0; u < 4; ++u) {
                accx += __builtin_amdgcn_cvt_f32_fp8((int)vv[u], 0) * ff[u];
                accy += __builtin_amdgcn_cvt_f32_fp8((int)vv[u], 1) * ff[u];
            }
        }
        for (; i < cnt; ++i) {
            int s0 = __shfl(s_l, i); float f0 = __shfl(c_l, i);
            unsigned short v0 = ((const unsigned short*)(xw8 + (size_t)s0 * F_DIM))[lane];
            accx += __builtin_amdgcn_cvt_f32_fp8((int)v0, 0) * f0;
            accy += __builtin_amdgcn_cvt_f32_fp8((int)v0, 1) * f0;
        }
    }

    float ivd = inv[node];
    unsigned short selfraw = ((const unsigned short*)(xw8 + (size_t)node * F_DIM))[lane];
    float s0 = __builtin_amdgcn_cvt_f32_fp8((int)selfraw, 0);
    float s1 = __builtin_amdgcn_cvt_f32_fp8((int)selfraw, 1);
    float vx = accx * ivd + s0 * ivd * ivd + b[lane * 2];
    float vy = accy * ivd + s1 * ivd * ivd + b[lane * 2 + 1];
    vx = vx > 0.f ? vx : expf(vx) - 1.f;
    vy = vy > 0.f ? vy : expf(vy) - 1.f;
    f16x2 o; o[0] = (_Float16)vx; o[1] = (_Float16)vy;
    ((f16x2*)(h1c + (size_t)ci * F_DIM))[lane] = o;
}

// ---- layer-2 gather over rows [0,U) (fp16 compact rows), 8-way MLP ----
__global__ __launch_bounds__(256) void gather_l2_kernel(const _Float16* __restrict__ xwc,
                                                        const float* __restrict__ inv,
                                                        const int* __restrict__ rp,
                                                        const int* __restrict__ col,
                                                        const int* __restrict__ remap,
                                                        const float* __restrict__ b,
                                                        float* __restrict__ out) {
    int node = blockIdx.x * 4 + (threadIdx.x >> 6);
    if (node >= U_USERS) return;
    int lane = threadIdx.x & 63;
    int start = (node == 0) ? 0 : rp[node - 1];
    int end = rp[node];

    float accx = 0.f, accy = 0.f;
    for (int base = start; base < end; base += 64) {
        int j = base + lane;
        int r_l = 0; float c_l = 0.f;
        if (j < end) { int s = __builtin_nontemporal_load(col + j); c_l = inv[s]; r_l = remap[s]; }
        int cnt = min(64, end - base);
        int i = 0;
        for (; i + 8 <= cnt; i += 8) {
            int rr[8]; float ff[8]; f16x2 vv[8];
#pragma unroll
            for (int u = 0; u < 8; ++u) { rr[u] = __shfl(r_l, i + u); ff[u] = __shfl(c_l, i + u); }
#pragma unroll
            for (int u = 0; u < 8; ++u) vv[u] = ((const f16x2*)(xwc + (size_t)rr[u] * F_DIM))[lane];
#pragma unroll
            for (int u = 0; u < 8; ++u) { accx += (float)vv[u][0] * ff[u]; accy += (float)vv[u][1] * ff[u]; }
        }
        for (; i + 4 <= cnt; i += 4) {
            int rr[4]; float ff[4]; f16x2 vv[4];
#pragma unroll
            for (int u = 0; u < 4; ++u) { rr[u] = __shfl(r_l, i + u); ff[u] = __shfl(c_l, i + u); }
#pragma unroll
            for (int u = 0; u < 4; ++u) vv[u] = ((const f16x2*)(xwc + (size_t)rr[u] * F_DIM))[lane];
#pragma unroll
            for (int u = 0; u < 4; ++u) { accx += (float)vv[u][0] * ff[u]; accy += (float)vv[u][1] * ff[u]; }
        }
        for (; i < cnt; ++i) {
            int r0 = __shfl(r_l, i); float f0 = __shfl(c_l, i);
            f16x2 v0 = ((const f16x2*)(xwc + (size_t)r0 * F_DIM))[lane];
            accx += (float)v0[0] * f0;
            accy += (float)v0[1] * f0;
        }
    }

    float ivd = inv[node];
    f16x2 self = ((const f16x2*)(xwc + (size_t)node * F_DIM))[lane];  // remap[node]==node for node<U
    float vx = accx * ivd + (float)self[0] * ivd * ivd + b[lane * 2];
    float vy = accy * ivd + (float)self[1] * ivd * ivd + b[lane * 2 + 1];
    vx = vx > 0.f ? vx : expf(vx) - 1.f;
    vy = vy > 0.f ? vy : expf(vy) - 1.f;
    ((float2*)(out + (size_t)node * F_DIM))[lane] = make_float2(vx, vy);
}

extern "C" void kernel_launch(void* const* d_in, const int* in_sizes, int n_in,
                              void* d_out, int out_size, void* d_ws, size_t ws_size,
                              hipStream_t stream) {
    const float* x  = (const float*)d_in[0];
    const int*   ei = (const int*)d_in[1];   // [2, E] int32
    const float* W1 = (const float*)d_in[2];
    const float* b1 = (const float*)d_in[3];
    const float* W2 = (const float*)d_in[4];
    const float* b2 = (const float*)d_in[5];
    float* out = (float*)d_out;

    int n = in_sizes[0] / F_DIM;   // 100000
    int E = in_sizes[1] / 2;       // 3200000
    const int* srcI = ei;
    const int* dstI = ei + E;

    // workspace layout (~65 MB)
    unsigned char* xw8 = (unsigned char*)d_ws;       // n*128 fp8 (12.8MB)
    _Float16* xwc = (_Float16*)(xw8 + (size_t)n * F_DIM);   // NFCAP*128 f16 (12.3MB)
    _Float16* h1c = xwc + (size_t)NFCAP * F_DIM;     // NFCAP*128 f16 (12.3MB)
    float* inv   = (float*)(h1c + (size_t)NFCAP * F_DIM);  // n f
    int* fr      = (int*)(inv + n);                  // n
    int* remap   = fr + n;                           // n
    int* rp      = remap + n;                        // n
    int* flist   = rp + n;                           // NFCAP
    int* nf_dev  = flist + NFCAP;                    // 16 ints
    int* col     = nf_dev + 16;                      // E
    unsigned int* partialH = (unsigned int*)(col + E);  // PSLICE*HW (12.8MB)
    unsigned int* bitsG = partialH + (size_t)PSLICE * HW;  // BMW words
    unsigned long long* desc = (unsigned long long*)(bitsG + BMW);  // NBPS u64

    zero_kernel<<<(n / 4 + 255) / 256, 256, 0, stream>>>(fr, desc, n);

    hist_kernel<<<PSLICE, 1024, 0, stream>>>(srcI, dstI, partialH, fr, E, n);

    prep_scan_kernel<<<NBPS, 1024, 0, stream>>>(partialH, fr, inv, rp, remap,
                                                flist, nf_dev, bitsG, desc, n);

    // fused, role-interleaved gemm1 (fp8 out) + fill_csr
    int fillBlocks = (E / 4 + 255) / 256;    // 3125
    int gemmBlocks = (n + 63) / 64;          // 1563
    gemm_fill_kernel<<<fillBlocks + gemmBlocks, 256, 0, stream>>>(
        x, W1, xw8, out, n, gemmBlocks, fillBlocks + gemmBlocks,
        srcI, dstI, bitsG, rp, col, E, n);

    gather_l1_kernel<<<(NFCAP + 3) / 4, 256, 0, stream>>>(xw8, inv, rp, col, flist, nf_dev, b1, h1c);

    gemm_f16_dyn_kernel<<<(NFCAP + 63) / 64, 256, 0, stream>>>(h1c, W2, xwc, nf_dev);
    gather_l2_kernel<<<(U_USERS + 3) / 4, 256, 0, stream>>>(xwc, inv, rp, col, remap, b2, out);
}